// Round 7
// baseline (279.954 us; speedup 1.0000x reference)
//
#include <hip/hip_runtime.h>
#include <math.h>

// r7: spill-free MFMA megakernel. Design target: <=128 VGPR (toolchain pins
// 512-thr kernels at 128). Changes vs r6:
//  - attention: flash over 8 k-tiles (sacc[2] not sacc[16][2]); K AND VT in
//    LDS (16+16KB) enabled by sX [256][128] + 16B-granular XOR swizzle.
//  - FFN: H staged in per-wave LDS chunk (u=64), w2 B-frags = direct ds_read
//    (no bpermute); output-d in 2 halves (w1 recomputed, oacc 32 regs).
//  - per-16-row LN stats: lane owns its frag row's stats, no bpermute.
//  - make_bfrag: pack f32->f16x2 BEFORE permute (8 DS-ops, was 16).

#define SQRT_D 11.313708498984761f
#define PE_C   0.14391156831212787f
#define INV_SQRT_DK 0.17677669529663687f
// element index into swizzled sX[256][128]; XOR flips bits 2..5 only -> f32x4
// groups stay contiguous, column reads spread over 8 bank-groups.
#define XF(j,d) (((j) << 7) + ((d) ^ (((j) & 15) << 2)))

typedef _Float16 f16x8 __attribute__((ext_vector_type(8)));
typedef float    f32x4 __attribute__((ext_vector_type(4)));

#define MFMA(a, b, c) __builtin_amdgcn_mfma_f32_16x16x32_f16((a), (b), (c), 0, 0, 0)

__device__ __forceinline__ unsigned pack2(float a, float b) {
  union { _Float16 h; unsigned short s; } ua, ub;
  ua.h = (_Float16)a; ub.h = (_Float16)b;
  return (unsigned)ua.s | ((unsigned)ub.s << 16);
}

__device__ __forceinline__ unsigned bperm(int addr, unsigned v) {
  return (unsigned)__builtin_amdgcn_ds_bpermute(addr, (int)v);
}

__device__ __forceinline__ f16x8 u4f16x8(unsigned u0, unsigned u1, unsigned u2, unsigned u3) {
  union { unsigned u[4]; f16x8 f; } x;
  x.u[0] = u0; x.u[1] = u1; x.u[2] = u2; x.u[3] = u3;
  return x.f;
}

// B-frag from two C/D tiles. elem j<4 = reg j of lane aLo, j>=4 = reg j&3 of
// lane aHi, tile cA for dest lanes <32 (hiSel=0), cB for >=32. (r6-verified.)
__device__ __forceinline__ f16x8 make_bfrag(f32x4 cA, f32x4 cB, int aLo, int aHi, int hiSel) {
  unsigned a0 = pack2(cA[0], cA[1]), a1 = pack2(cA[2], cA[3]);
  unsigned b0 = pack2(cB[0], cB[1]), b1 = pack2(cB[2], cB[3]);
  unsigned lA0 = bperm(aLo, a0), lA1 = bperm(aLo, a1);
  unsigned hA0 = bperm(aHi, a0), hA1 = bperm(aHi, a1);
  unsigned lB0 = bperm(aLo, b0), lB1 = bperm(aLo, b1);
  unsigned hB0 = bperm(aHi, b0), hB1 = bperm(aHi, b1);
  return u4f16x8(hiSel ? lB0 : lA0, hiSel ? lB1 : lA1,
                 hiSel ? hB0 : hA0, hiSel ? hB1 : hA1);
}

// ---------------- K0: weight f32 -> f16 ----------------
struct P0 { const float *qw, *kw, *vw, *ow, *w1, *w2; _Float16* dst; };

__global__ __launch_bounds__(256) void convf16(P0 p) {
  const int idx = blockIdx.x * 256 + threadIdx.x;
  float v;
  if      (idx <  32768) v = p.qw[idx];
  else if (idx <  65536) v = p.kw[idx -  32768];
  else if (idx <  98304) v = p.vw[idx -  65536];
  else if (idx < 131072) v = p.ow[idx -  98304];
  else if (idx < 262144) v = p.w1[idx - 131072];
  else                   v = p.w2[idx - 262144];
  p.dst[idx] = (_Float16)v;
}

// ---------------- K1: prep (verified r3) ----------------
struct P1 {
  const float* src; const int* t;
  const float* fc_w; const float* fc_b; const float* gc_w; const float* gc_b;
  const float* ln_w; const float* ln_b;
  const float* n1a; const float* n1b;
  const float* vw; const float* vb; const float* ow; const float* ob;
  float* x0; float* a0;
};

__device__ __forceinline__ float rowReduceSum(float v, volatile float* red, int d) {
#pragma unroll
  for (int off = 32; off > 0; off >>= 1) v += __shfl_xor(v, off, 64);
  if ((d & 63) == 0) red[d >> 6] = v;
  __syncthreads();
  float r = red[0] + red[1];
  __syncthreads();
  return r;
}

__device__ __forceinline__ float dot128s(const float* __restrict__ w,
                                         const float* __restrict__ xs) {
  const float4* __restrict__ w4 = (const float4*)w;
  const float4* __restrict__ x4 = (const float4*)xs;
  float a0 = 0.f, a1 = 0.f, a2 = 0.f, a3 = 0.f;
#pragma unroll
  for (int k = 0; k < 32; k += 4) {
    float4 xv0 = x4[k + 0], xv1 = x4[k + 1], xv2 = x4[k + 2], xv3 = x4[k + 3];
    float4 wv0 = w4[k + 0], wv1 = w4[k + 1], wv2 = w4[k + 2], wv3 = w4[k + 3];
    a0 = fmaf(wv0.w, xv0.w, fmaf(wv0.z, xv0.z, fmaf(wv0.y, xv0.y, fmaf(wv0.x, xv0.x, a0))));
    a1 = fmaf(wv1.w, xv1.w, fmaf(wv1.z, xv1.z, fmaf(wv1.y, xv1.y, fmaf(wv1.x, xv1.x, a1))));
    a2 = fmaf(wv2.w, xv2.w, fmaf(wv2.z, xv2.z, fmaf(wv2.y, xv2.y, fmaf(wv2.x, xv2.x, a2))));
    a3 = fmaf(wv3.w, xv3.w, fmaf(wv3.z, xv3.z, fmaf(wv3.y, xv3.y, fmaf(wv3.x, xv3.x, a3))));
  }
  return (a0 + a1) + (a2 + a3);
}

__global__ __launch_bounds__(256) void prep(P1 p) {
  __shared__ __align__(16) float s_src[2][16];
  __shared__ __align__(16) float s_x2[2][128];
  __shared__ __align__(16) float s_y[2][128];
  __shared__ float s_red[2][2];

  const int tid = threadIdx.x;
  const int rl  = tid >> 7;
  const int d   = tid & 127;
  const int row = blockIdx.x * 2 + rl;
  volatile float* red = s_red[rl];

  if (d < 14) s_src[rl][d + 1] = p.src[row * 14 + d];
  if (d == 14) { s_src[rl][0] = 0.f; s_src[rl][15] = 0.f; }
  __syncthreads();

  const float fw0 = p.fc_w[3*d+0], fw1 = p.fc_w[3*d+1], fw2 = p.fc_w[3*d+2];
  const float gw0 = p.gc_w[3*d+0], gw1 = p.gc_w[3*d+1], gw2 = p.gc_w[3*d+2];
  const float fb = p.fc_b[d], gb = p.gc_b[d];
  float g = 0.f;
#pragma unroll
  for (int m = 0; m < 14; ++m) {
    float xm1 = s_src[rl][m], x0v = s_src[rl][m+1], xp1 = s_src[rl][m+2];
    float f  = fmaf(fw2, xp1, fmaf(fw1, x0v, fmaf(fw0, xm1, fb)));
    float ga = fmaf(gw2, xp1, fmaf(gw1, x0v, fmaf(gw0, xm1, gb)));
    g = fmaf(f, 1.f / (1.f + expf(-ga)), g);
  }
  g *= (1.f / 14.f);

  float mu = rowReduceSum(g, red, d) * (1.f / 128.f);
  float cg = g - mu;
  float var = rowReduceSum(cg * cg, red, d) * (1.f / 128.f);
  float x = fmaf(p.ln_w[d], cg * rsqrtf(var + 1e-5f), p.ln_b[d]);

  const int tval = *p.t;
  {
    int i2 = d >> 1;
    float arg = (float)tval * expf((float)i2 * -PE_C);
    float pe = (d & 1) ? cosf(arg) : sinf(arg);
    x = fmaf(x, SQRT_D, pe);
  }
  p.x0[row * 128 + d] = x;

  float mu1 = rowReduceSum(x, red, d) * (1.f / 128.f);
  float c1 = x - mu1;
  float v1 = rowReduceSum(c1 * c1, red, d) * (1.f / 127.f);
  s_x2[rl][d] = fmaf(p.n1a[d], c1 / (sqrtf(v1) + 1e-6f), p.n1b[d]);
  __syncthreads();

  float y = p.vb[d] + dot128s(p.vw + d * 128, s_x2[rl]);
  s_y[rl][d] = y;
  __syncthreads();
  p.a0[row * 128 + d] = p.ob[d] + dot128s(p.ow + d * 128, s_y[rl]);
}

// ---------------- K2: per-batch MFMA megakernel ----------------
struct P2 {
  const float* x0; const float* a0;
  const _Float16 *wq, *wk, *wvv, *wo, *w1h, *w2h;
  const float *qb, *kb, *vb, *ob;
  const float *n1a, *n1b, *n2a, *n2b;
  const float *b1, *b2;
  const float *fna, *fnb, *out_w, *out_b;
  float* out;
};

// norm (_norm: ddof=1, eps on std) of 16 rows (pass nt) -> B-frags out[4].
// Lane l owns row l&15's stats directly (quarter-sum + 2 shfls). No bpermute.
__device__ __forceinline__ void build_x2_pass(const float* sX, int strip, int nt, int l,
    const float* __restrict__ na, const float* __restrict__ nb, f16x8 out[4]) {
  const int l15 = l & 15, q = l >> 4;
  const int row = strip + nt * 16 + l15;
  float sum = 0.f, sq = 0.f;
#pragma unroll
  for (int c4 = 0; c4 < 8; ++c4) {
    f32x4 v = *(const f32x4*)&sX[XF(row, q * 32 + c4 * 4)];
#pragma unroll
    for (int e = 0; e < 4; ++e) { sum += v[e]; sq = fmaf(v[e], v[e], sq); }
  }
  sum += __shfl_xor(sum, 16); sum += __shfl_xor(sum, 32);
  sq  += __shfl_xor(sq, 16);  sq  += __shfl_xor(sq, 32);
  const float mu = sum * (1.f / 128.f);
  const float var = fmaf(-sum, mu, sq) * (1.f / 127.f);
  const float inv = 1.f / (sqrtf(var) + 1e-6f);
#pragma unroll
  for (int kt = 0; kt < 4; ++kt) {
    const int d0 = kt * 32 + q * 8;
    f32x4 xA = *(const f32x4*)&sX[XF(row, d0)];
    f32x4 xB = *(const f32x4*)&sX[XF(row, d0 + 4)];
    f32x4 nA = *(const f32x4*)&na[d0], nB = *(const f32x4*)&na[d0 + 4];
    f32x4 bA = *(const f32x4*)&nb[d0], bB = *(const f32x4*)&nb[d0 + 4];
    float v0 = fmaf(nA[0] * inv, xA[0] - mu, bA[0]);
    float v1 = fmaf(nA[1] * inv, xA[1] - mu, bA[1]);
    float v2 = fmaf(nA[2] * inv, xA[2] - mu, bA[2]);
    float v3 = fmaf(nA[3] * inv, xA[3] - mu, bA[3]);
    float v4 = fmaf(nB[0] * inv, xB[0] - mu, bB[0]);
    float v5 = fmaf(nB[1] * inv, xB[1] - mu, bB[1]);
    float v6 = fmaf(nB[2] * inv, xB[2] - mu, bB[2]);
    float v7 = fmaf(nB[3] * inv, xB[3] - mu, bB[3]);
    out[kt] = u4f16x8(pack2(v0, v1), pack2(v2, v3), pack2(v4, v5), pack2(v6, v7));
  }
}

// norm2 + FFN, residual into sX. sH = this wave's 4KB LDS chunk ([32][64] f16,
// XOR-swizzled). Output-d in 2 halves (oacc 32 regs); w1 recomputed per half.
__device__ __forceinline__ void ffn_phase(float* sX, _Float16* sH, int strip, int l,
    const float* __restrict__ na, const float* __restrict__ nb,
    const _Float16* __restrict__ w1, const float* __restrict__ b1,
    const _Float16* __restrict__ w2, const float* __restrict__ b2) {
  const int l15 = l & 15, lg = l >> 4;
  f16x8 x2f[4][2];
#pragma unroll
  for (int nt = 0; nt < 2; ++nt) {
    f16x8 tmp[4];
    build_x2_pass(sX, strip, nt, l, na, nb, tmp);
#pragma unroll
    for (int kt = 0; kt < 4; ++kt) x2f[kt][nt] = tmp[kt];
  }
#pragma unroll 1
  for (int dh = 0; dh < 2; ++dh) {
    f32x4 oacc[4][2];
#pragma unroll
    for (int mt = 0; mt < 4; ++mt) {
      f32x4 b = *(const f32x4*)&b2[dh * 64 + mt * 16 + lg * 4];
      oacc[mt][0] = b; oacc[mt][1] = b;
    }
#pragma unroll 1
    for (int c = 0; c < 8; ++c) {
      f32x4 hacc[4][2];
#pragma unroll
      for (int mt = 0; mt < 4; ++mt) {
        f32x4 b = *(const f32x4*)&b1[c * 64 + mt * 16 + lg * 4];
        hacc[mt][0] = b; hacc[mt][1] = b;
      }
#pragma unroll
      for (int mt = 0; mt < 4; ++mt)
#pragma unroll
        for (int kt = 0; kt < 4; ++kt) {
          f16x8 a = *(const f16x8*)(w1 + (c * 64 + mt * 16 + l15) * 128 + kt * 32 + lg * 8);
          hacc[mt][0] = MFMA(a, x2f[kt][0], hacc[mt][0]);
          hacc[mt][1] = MFMA(a, x2f[kt][1], hacc[mt][1]);
        }
      // relu + packed write to own sH chunk
#pragma unroll
      for (int mt = 0; mt < 4; ++mt)
#pragma unroll
        for (int nt = 0; nt < 2; ++nt) {
          const int row = nt * 16 + l15;
          const int ub = mt * 16 + lg * 4;
          uint2 w;
          w.x = pack2(fmaxf(hacc[mt][nt][0], 0.f), fmaxf(hacc[mt][nt][1], 0.f));
          w.y = pack2(fmaxf(hacc[mt][nt][2], 0.f), fmaxf(hacc[mt][nt][3], 0.f));
          *(uint2*)(sH + row * 64 + (ub ^ ((row & 7) << 3))) = w;
        }
      // w2 accumulate: B-frags straight from LDS (16B reads, no bpermute)
#pragma unroll
      for (int kt = 0; kt < 2; ++kt) {
        const int r0 = l15, r1 = 16 + l15;
        f16x8 hf0 = *(const f16x8*)(sH + r0 * 64 + ((kt * 32 + lg * 8) ^ ((r0 & 7) << 3)));
        f16x8 hf1 = *(const f16x8*)(sH + r1 * 64 + ((kt * 32 + lg * 8) ^ ((r1 & 7) << 3)));
#pragma unroll
        for (int mt = 0; mt < 4; ++mt) {
          f16x8 a = *(const f16x8*)(w2 + (dh * 64 + mt * 16 + l15) * 512 + c * 64 + kt * 32 + lg * 8);
          oacc[mt][0] = MFMA(a, hf0, oacc[mt][0]);
          oacc[mt][1] = MFMA(a, hf1, oacc[mt][1]);
        }
      }
    }
    // residual
#pragma unroll
    for (int mt = 0; mt < 4; ++mt)
#pragma unroll
      for (int nt = 0; nt < 2; ++nt) {
        const int row = strip + nt * 16 + l15;
        float* dst = &sX[XF(row, dh * 64 + mt * 16 + lg * 4)];
        f32x4 v = *(const f32x4*)dst;
        v += oacc[mt][nt];
        *(f32x4*)dst = v;
      }
  }
}

__global__ __launch_bounds__(512) void batchk(P2 p) {
  __shared__ __align__(16) float sX[32768];        // 128 KB, XF-swizzled
  __shared__ __align__(16) _Float16 sKV[16384];    // 32 KB: FFN sH | attn K+VT

  const int t = threadIdx.x;
  const int i = blockIdx.x;
  const int l = t & 63;
  const int wv = t >> 6;
  const int strip = wv * 32;
  const int l15 = l & 15;
  const int lg = l >> 4;
  const int hiSel = (l >> 5) & 1;
  const int aLo = ((((lg & 1) * 2 + 0) * 16) + l15) * 4;
  const int aHi = ((((lg & 1) * 2 + 1) * 16) + l15) * 4;

  // ---- Phase A: X[i,j,:] = x0[j] + a0[i] (own strip rows) ----
  {
    const int j = t >> 1, hf = t & 1;
    const float* xr = p.x0 + j * 128 + hf * 64;
    const float* ar = p.a0 + i * 128 + hf * 64;
#pragma unroll
    for (int c = 0; c < 16; ++c) {
      f32x4 a = *(const f32x4*)(xr + c * 4);
      f32x4 b = *(const f32x4*)(ar + c * 4);
      a += b;
      *(f32x4*)&sX[XF(j, hf * 64 + c * 4)] = a;
    }
  }

  // ---- FFN0 (own strip; per-wave sH chunk) ----
  ffn_phase(sX, sKV + wv * 2048, strip, l, p.n2a, p.n2b, p.w1h, p.b1, p.w2h, p.b2);
  __syncthreads();  // sKV switches role FFN-sH -> attn K/VT

  // ---- layer-1 attention: flash over k-tiles ----
  {
    const _Float16* __restrict__ qw = p.wq + 16384;
    const _Float16* __restrict__ kw = p.wk + 16384;
    const _Float16* __restrict__ vw = p.wvv + 16384;
    const _Float16* __restrict__ ow = p.wo + 16384;
    const float* __restrict__ qb1 = p.qb + 128;
    const float* __restrict__ kb1 = p.kb + 128;
    const float* __restrict__ vb1 = p.vb + 128;
    const float* __restrict__ ob1 = p.ob + 128;
    _Float16* sK  = sKV;           // [256][32] f16, swz d^((j&3)<<3)
    _Float16* sVT = sKV + 8192;    // [32][256] f16, swz j^((d&7)<<3)

    f16x8 x2f[4][2];
#pragma unroll
    for (int nt = 0; nt < 2; ++nt) {
      f16x8 tmp[4];
      build_x2_pass(sX, strip, nt, l, p.n1a + 128, p.n1b + 128, tmp);
#pragma unroll
      for (int kt = 0; kt < 4; ++kt) x2f[kt][nt] = tmp[kt];
    }

#pragma unroll 1
    for (int h = 0; h < 4; ++h) {
      // ---- K gen (own strip) ----
      {
        f32x4 kacc[2][2];
#pragma unroll
        for (int mt = 0; mt < 2; ++mt) {
          f32x4 b = *(const f32x4*)&kb1[h * 32 + mt * 16 + lg * 4];
          kacc[mt][0] = b; kacc[mt][1] = b;
        }
#pragma unroll
        for (int mt = 0; mt < 2; ++mt)
#pragma unroll
          for (int kt = 0; kt < 4; ++kt) {
            f16x8 a = *(const f16x8*)(kw + (h * 32 + mt * 16 + l15) * 128 + kt * 32 + lg * 8);
            kacc[mt][0] = MFMA(a, x2f[kt][0], kacc[mt][0]);
            kacc[mt][1] = MFMA(a, x2f[kt][1], kacc[mt][1]);
          }
#pragma unroll
        for (int mt = 0; mt < 2; ++mt)
#pragma unroll
          for (int nt = 0; nt < 2; ++nt) {
            const int j = strip + nt * 16 + l15;
            const int db = mt * 16 + lg * 4;
            uint2 w;
            w.x = pack2(kacc[mt][nt][0], kacc[mt][nt][1]);
            w.y = pack2(kacc[mt][nt][2], kacc[mt][nt][3]);
            *(uint2*)(sK + j * 32 + (db ^ ((j & 3) << 3))) = w;
          }
      }
      // ---- V gen -> VT (own strip columns) ----
      {
        f32x4 vacc[2][2];
#pragma unroll
        for (int mt = 0; mt < 2; ++mt) {
          f32x4 b = *(const f32x4*)&vb1[h * 32 + mt * 16 + lg * 4];
          vacc[mt][0] = b; vacc[mt][1] = b;
        }
#pragma unroll
        for (int mt = 0; mt < 2; ++mt)
#pragma unroll
          for (int kt = 0; kt < 4; ++kt) {
            f16x8 a = *(const f16x8*)(vw + (h * 32 + mt * 16 + l15) * 128 + kt * 32 + lg * 8);
            vacc[mt][0] = MFMA(a, x2f[kt][0], vacc[mt][0]);
            vacc[mt][1] = MFMA(a, x2f[kt][1], vacc[mt][1]);
          }
#pragma unroll
        for (int mt = 0; mt < 2; ++mt)
#pragma unroll
          for (int nt = 0; nt < 2; ++nt)
#pragma unroll
            for (int e = 0; e < 4; ++e) {
              const int d = mt * 16 + lg * 4 + e;
              const int j = strip + nt * 16 + l15;
              sVT[d * 256 + (j ^ ((d & 7) << 3))] = (_Float16)vacc[mt][nt][e];
            }
      }
      __syncthreads();  // K/VT visible

#pragma unroll
      for (int nt = 0; nt < 2; ++nt) {
        // ---- Q gen for pass rows (scale folded) ----
        f16x8 qf;
        {
          f32x4 qacc[2];
#pragma unroll
          for (int mt = 0; mt < 2; ++mt)
            qacc[mt] = *(const f32x4*)&qb1[h * 32 + mt * 16 + lg * 4];
#pragma unroll
          for (int mt = 0; mt < 2; ++mt)
#pragma unroll
            for (int kt = 0; kt < 4; ++kt) {
              f16x8 a = *(const f16x8*)(qw + (h * 32 + mt * 16 + l15) * 128 + kt * 32 + lg * 8);
              qacc[mt] = MFMA(a, x2f[kt][nt], qacc[mt]);
            }
#pragma unroll
          for (int mt = 0; mt < 2; ++mt)
#pragma unroll
            for (int e = 0; e < 4; ++e) qacc[mt][e] *= INV_SQRT_DK;
          qf = make_bfrag(qacc[0], qacc[1], aLo, aHi, hiSel);
        }
        // ---- flash over 8 k-tiles ----
        float mrun = -3e38f, lsum = 0.f;
        f32x4 oacc[2];
        { f32x4 z = {0.f, 0.f, 0.f, 0.f}; oacc[0] = z; oacc[1] = z; }
#pragma unroll 1
        for (int ktile = 0; ktile < 8; ++ktile) {
          f32x4 sacc[2];
#pragma unroll
          for (int mt2 = 0; mt2 < 2; ++mt2) {
            const int k = ktile * 32 + mt2 * 16 + l15;
            f16x8 a = *(const f16x8*)(sK + k * 32 + ((lg * 8) ^ ((k & 3) << 3)));
            f32x4 z = {0.f, 0.f, 0.f, 0.f};
            sacc[mt2] = MFMA(a, qf, z);
          }
          float tm = -3e38f;
#pragma unroll
          for (int mt2 = 0; mt2 < 2; ++mt2)
#pragma unroll
            for (int e = 0; e < 4; ++e) tm = fmaxf(tm, sacc[mt2][e]);
          tm = fmaxf(tm, __shfl_xor(tm, 16));
          tm = fmaxf(tm, __shfl_xor(tm, 32));
          const float mnew = fmaxf(mrun, tm);
          const float corr = __expf(mrun - mnew);
          float ts = 0.f;
#pragma unroll
          for (int mt2 = 0; mt2 < 2; ++mt2)
#pragma unroll
            for (int e = 0; e < 4; ++e) {
              float ev = __expf(sacc[mt2][e] - mnew);
              sacc[mt2][e] = ev;
              ts += ev;
            }
          ts += __shfl_xor(ts, 16);
          ts += __shfl_xor(ts, 32);
          lsum = fmaf(lsum, corr, ts);
          oacc[0] *= corr; oacc[1] *= corr;
          f16x8 pf = make_bfrag(sacc[0], sacc[1], aLo, aHi, hiSel);
#pragma unroll
          for (int mt2 = 0; mt2 < 2; ++mt2) {
            const int d = mt2 * 16 + l15;
            f16x8 a = *(const f16x8*)(sVT + d * 256 + ((ktile * 32 + lg * 8) ^ ((d & 7) << 3)));
            oacc[mt2] = MFMA(a, pf, oacc[mt2]);
          }
          mrun = mnew;
        }
        const float linv = 1.f / lsum;
        oacc[0] *= linv; oacc[1] *= linv;
        f16x8 of = make_bfrag(oacc[0], oacc[1], aLo, aHi, hiSel);
        // ---- Z = ow_h @ O^T, residual into sX ----
        f32x4 zacc[8];
#pragma unroll
        for (int mt = 0; mt < 8; ++mt) {
          if (h == 0) zacc[mt] = *(const f32x4*)&ob1[mt * 16 + lg * 4];
          else { f32x4 z = {0.f, 0.f, 0.f, 0.f}; zacc[mt] = z; }
        }
#pragma unroll
        for (int mt = 0; mt < 8; ++mt) {
          f16x8 a = *(const f16x8*)(ow + (mt * 16 + l15) * 128 + h * 32 + lg * 8);
          zacc[mt] = MFMA(a, of, zacc[mt]);
        }
        const int row = strip + nt * 16 + l15;
#pragma unroll
        for (int mt = 0; mt < 8; ++mt) {
          float* dst = &sX[XF(row, mt * 16 + lg * 4)];
          f32x4 v = *(const f32x4*)dst;
          v += zacc[mt];
          *(f32x4*)dst = v;
        }
      }
      __syncthreads();  // flash reads done before next head / FFN1 overwrite
    }
  }

  // ---- FFN1 ----
  ffn_phase(sX, sKV + wv * 2048, strip, l, p.n2a + 128, p.n2b + 128,
            p.w1h + 65536, p.b1 + 512, p.w2h + 65536, p.b2 + 128);

  // ---- final norm + output projection ----
  {
    const int r = strip + (l & 31), hf = l >> 5;
    float sum = 0.f, sq = 0.f;
#pragma unroll
    for (int c = 0; c < 16; ++c) {
      f32x4 v = *(const f32x4*)&sX[XF(r, hf * 64 + c * 4)];
#pragma unroll
      for (int e = 0; e < 4; ++e) { sum += v[e]; sq = fmaf(v[e], v[e], sq); }
    }
    sum += __shfl_xor(sum, 32);
    sq  += __shfl_xor(sq, 32);
    float mu = sum * (1.f / 128.f);
    float var = fmaf(-sum, mu, sq) * (1.f / 127.f);
    float inv = 1.f / (sqrtf(var) + 1e-6f);
    float os = 0.f;
#pragma unroll
    for (int c = 0; c < 16; ++c) {
      f32x4 x  = *(const f32x4*)&sX[XF(r, hf * 64 + c * 4)];
      f32x4 fa = *(const f32x4*)&p.fna[hf * 64 + c * 4];
      f32x4 fb = *(const f32x4*)&p.fnb[hf * 64 + c * 4];
      f32x4 wo = *(const f32x4*)&p.out_w[hf * 64 + c * 4];
#pragma unroll
      for (int e = 0; e < 4; ++e)
        os = fmaf(fmaf(fa[e] * inv, x[e] - mu, fb[e]), wo[e], os);
    }
    os += __shfl_xor(os, 32);
    if (l < 32) p.out[i * 256 + r] = os + p.out_b[0];
  }
}

// ---------------- host ----------------
extern "C" void kernel_launch(void* const* d_in, const int* in_sizes, int n_in,
                              void* d_out, int out_size, void* d_ws, size_t ws_size,
                              hipStream_t stream) {
  float* x0 = (float*)d_ws;                           // 32768 f32
  float* a0 = x0 + 32768;                             // 32768 f32
  _Float16* W16 = (_Float16*)((char*)d_ws + 262144);  // 393216 halves

  P0 p0;
  p0.qw = (const float*)d_in[8];  p0.kw = (const float*)d_in[10];
  p0.vw = (const float*)d_in[12]; p0.ow = (const float*)d_in[14];
  p0.w1 = (const float*)d_in[20]; p0.w2 = (const float*)d_in[22];
  p0.dst = W16;
  convf16<<<dim3(1536), dim3(256), 0, stream>>>(p0);

  P1 p1;
  p1.src  = (const float*)d_in[0];
  p1.t    = (const int*)  d_in[1];
  p1.fc_w = (const float*)d_in[2];  p1.fc_b = (const float*)d_in[3];
  p1.gc_w = (const float*)d_in[4];  p1.gc_b = (const float*)d_in[5];
  p1.ln_w = (const float*)d_in[6];  p1.ln_b = (const float*)d_in[7];
  p1.n1a  = (const float*)d_in[16]; p1.n1b  = (const float*)d_in[17];
  p1.vw   = (const float*)d_in[12]; p1.vb   = (const float*)d_in[13];
  p1.ow   = (const float*)d_in[14]; p1.ob   = (const float*)d_in[15];
  p1.x0 = x0; p1.a0 = a0;
  prep<<<dim3(128), dim3(256), 0, stream>>>(p1);

  P2 p2;
  p2.x0 = x0; p2.a0 = a0;
  p2.wq  = W16;
  p2.wk  = W16 + 32768;
  p2.wvv = W16 + 65536;
  p2.wo  = W16 + 98304;
  p2.w1h = W16 + 131072;
  p2.w2h = W16 + 262144;
  p2.qb = (const float*)d_in[9];  p2.kb = (const float*)d_in[11];
  p2.vb = (const float*)d_in[13]; p2.ob = (const float*)d_in[15];
  p2.n1a = (const float*)d_in[16]; p2.n1b = (const float*)d_in[17];
  p2.n2a = (const float*)d_in[18]; p2.n2b = (const float*)d_in[19];
  p2.b1 = (const float*)d_in[21];  p2.b2 = (const float*)d_in[23];
  p2.fna = (const float*)d_in[24]; p2.fnb = (const float*)d_in[25];
  p2.out_w = (const float*)d_in[26]; p2.out_b = (const float*)d_in[27];
  p2.out = (float*)d_out;
  batchk<<<dim3(256), dim3(512), 0, stream>>>(p2);
}

// Round 8
// 142.142 us; speedup vs baseline: 1.9695x; 1.9695x over previous
//
#include <hip/hip_runtime.h>
#include <math.h>

// r8: LDS-staged weights. r7 post-mortem: spills gone (WRITE 256B) but
// 277us with MfmaUtil 10% => L2-bound on weight A-frags (2048 MFMA/wave x
// 1KB/read x 8 waves x 256 blocks ~ 4.3GB L2 ~ 125us). Fix: per-phase
// cooperative staging of weight chunks into the 32KB aux; A-frags now
// ds_read_b128 with granule-XOR swizzle. FFN restructured: w1 chunk staged+
// computed ONCE (no per-dh recompute); partial w2 output accumulates into sX.

#define SQRT_D 11.313708498984761f
#define PE_C   0.14391156831212787f
#define INV_SQRT_DK 0.17677669529663687f
#define XF(j,d) (((j) << 7) + ((d) ^ (((j) & 15) << 2)))

typedef _Float16 f16x8 __attribute__((ext_vector_type(8)));
typedef float    f32x4 __attribute__((ext_vector_type(4)));

#define MFMA(a, b, c) __builtin_amdgcn_mfma_f32_16x16x32_f16((a), (b), (c), 0, 0, 0)

__device__ __forceinline__ unsigned pack2(float a, float b) {
  union { _Float16 h; unsigned short s; } ua, ub;
  ua.h = (_Float16)a; ub.h = (_Float16)b;
  return (unsigned)ua.s | ((unsigned)ub.s << 16);
}

__device__ __forceinline__ unsigned bperm(int addr, unsigned v) {
  return (unsigned)__builtin_amdgcn_ds_bpermute(addr, (int)v);
}

__device__ __forceinline__ f16x8 u4f16x8(unsigned u0, unsigned u1, unsigned u2, unsigned u3) {
  union { unsigned u[4]; f16x8 f; } x;
  x.u[0] = u0; x.u[1] = u1; x.u[2] = u2; x.u[3] = u3;
  return x.f;
}

// B-frag from two C/D tiles (r6/r7-verified).
__device__ __forceinline__ f16x8 make_bfrag(f32x4 cA, f32x4 cB, int aLo, int aHi, int hiSel) {
  unsigned a0 = pack2(cA[0], cA[1]), a1 = pack2(cA[2], cA[3]);
  unsigned b0 = pack2(cB[0], cB[1]), b1 = pack2(cB[2], cB[3]);
  unsigned lA0 = bperm(aLo, a0), lA1 = bperm(aLo, a1);
  unsigned hA0 = bperm(aHi, a0), hA1 = bperm(aHi, a1);
  unsigned lB0 = bperm(aLo, b0), lB1 = bperm(aLo, b1);
  unsigned hB0 = bperm(aHi, b0), hB1 = bperm(aHi, b1);
  return u4f16x8(hiSel ? lB0 : lA0, hiSel ? lB1 : lA1,
                 hiSel ? hB0 : hA0, hiSel ? hB1 : hA1);
}

// ---------------- K0: weight f32 -> f16 ----------------
struct P0 { const float *qw, *kw, *vw, *ow, *w1, *w2; _Float16* dst; };

__global__ __launch_bounds__(256) void convf16(P0 p) {
  const int idx = blockIdx.x * 256 + threadIdx.x;
  float v;
  if      (idx <  32768) v = p.qw[idx];
  else if (idx <  65536) v = p.kw[idx -  32768];
  else if (idx <  98304) v = p.vw[idx -  65536];
  else if (idx < 131072) v = p.ow[idx -  98304];
  else if (idx < 262144) v = p.w1[idx - 131072];
  else                   v = p.w2[idx - 262144];
  p.dst[idx] = (_Float16)v;
}

// ---------------- K1: prep (verified r3) ----------------
struct P1 {
  const float* src; const int* t;
  const float* fc_w; const float* fc_b; const float* gc_w; const float* gc_b;
  const float* ln_w; const float* ln_b;
  const float* n1a; const float* n1b;
  const float* vw; const float* vb; const float* ow; const float* ob;
  float* x0; float* a0;
};

__device__ __forceinline__ float rowReduceSum(float v, volatile float* red, int d) {
#pragma unroll
  for (int off = 32; off > 0; off >>= 1) v += __shfl_xor(v, off, 64);
  if ((d & 63) == 0) red[d >> 6] = v;
  __syncthreads();
  float r = red[0] + red[1];
  __syncthreads();
  return r;
}

__device__ __forceinline__ float dot128s(const float* __restrict__ w,
                                         const float* __restrict__ xs) {
  const float4* __restrict__ w4 = (const float4*)w;
  const float4* __restrict__ x4 = (const float4*)xs;
  float a0 = 0.f, a1 = 0.f, a2 = 0.f, a3 = 0.f;
#pragma unroll
  for (int k = 0; k < 32; k += 4) {
    float4 xv0 = x4[k + 0], xv1 = x4[k + 1], xv2 = x4[k + 2], xv3 = x4[k + 3];
    float4 wv0 = w4[k + 0], wv1 = w4[k + 1], wv2 = w4[k + 2], wv3 = w4[k + 3];
    a0 = fmaf(wv0.w, xv0.w, fmaf(wv0.z, xv0.z, fmaf(wv0.y, xv0.y, fmaf(wv0.x, xv0.x, a0))));
    a1 = fmaf(wv1.w, xv1.w, fmaf(wv1.z, xv1.z, fmaf(wv1.y, xv1.y, fmaf(wv1.x, xv1.x, a1))));
    a2 = fmaf(wv2.w, xv2.w, fmaf(wv2.z, xv2.z, fmaf(wv2.y, xv2.y, fmaf(wv2.x, xv2.x, a2))));
    a3 = fmaf(wv3.w, xv3.w, fmaf(wv3.z, xv3.z, fmaf(wv3.y, xv3.y, fmaf(wv3.x, xv3.x, a3))));
  }
  return (a0 + a1) + (a2 + a3);
}

__global__ __launch_bounds__(256) void prep(P1 p) {
  __shared__ __align__(16) float s_src[2][16];
  __shared__ __align__(16) float s_x2[2][128];
  __shared__ __align__(16) float s_y[2][128];
  __shared__ float s_red[2][2];

  const int tid = threadIdx.x;
  const int rl  = tid >> 7;
  const int d   = tid & 127;
  const int row = blockIdx.x * 2 + rl;
  volatile float* red = s_red[rl];

  if (d < 14) s_src[rl][d + 1] = p.src[row * 14 + d];
  if (d == 14) { s_src[rl][0] = 0.f; s_src[rl][15] = 0.f; }
  __syncthreads();

  const float fw0 = p.fc_w[3*d+0], fw1 = p.fc_w[3*d+1], fw2 = p.fc_w[3*d+2];
  const float gw0 = p.gc_w[3*d+0], gw1 = p.gc_w[3*d+1], gw2 = p.gc_w[3*d+2];
  const float fb = p.fc_b[d], gb = p.gc_b[d];
  float g = 0.f;
#pragma unroll
  for (int m = 0; m < 14; ++m) {
    float xm1 = s_src[rl][m], x0v = s_src[rl][m+1], xp1 = s_src[rl][m+2];
    float f  = fmaf(fw2, xp1, fmaf(fw1, x0v, fmaf(fw0, xm1, fb)));
    float ga = fmaf(gw2, xp1, fmaf(gw1, x0v, fmaf(gw0, xm1, gb)));
    g = fmaf(f, 1.f / (1.f + expf(-ga)), g);
  }
  g *= (1.f / 14.f);

  float mu = rowReduceSum(g, red, d) * (1.f / 128.f);
  float cg = g - mu;
  float var = rowReduceSum(cg * cg, red, d) * (1.f / 128.f);
  float x = fmaf(p.ln_w[d], cg * rsqrtf(var + 1e-5f), p.ln_b[d]);

  const int tval = *p.t;
  {
    int i2 = d >> 1;
    float arg = (float)tval * expf((float)i2 * -PE_C);
    float pe = (d & 1) ? cosf(arg) : sinf(arg);
    x = fmaf(x, SQRT_D, pe);
  }
  p.x0[row * 128 + d] = x;

  float mu1 = rowReduceSum(x, red, d) * (1.f / 128.f);
  float c1 = x - mu1;
  float v1 = rowReduceSum(c1 * c1, red, d) * (1.f / 127.f);
  s_x2[rl][d] = fmaf(p.n1a[d], c1 / (sqrtf(v1) + 1e-6f), p.n1b[d]);
  __syncthreads();

  float y = p.vb[d] + dot128s(p.vw + d * 128, s_x2[rl]);
  s_y[rl][d] = y;
  __syncthreads();
  p.a0[row * 128 + d] = p.ob[d] + dot128s(p.ow + d * 128, s_y[rl]);
}

// ---------------- K2: per-batch MFMA megakernel ----------------
struct P2 {
  const float* x0; const float* a0;
  const _Float16 *wq, *wk, *wvv, *wo, *w1h, *w2h;
  const float *qb, *kb, *vb, *ob;
  const float *n1a, *n1b, *n2a, *n2b;
  const float *b1, *b2;
  const float *fna, *fnb, *out_w, *out_b;
  float* out;
};

// norm (_norm: ddof=1, eps on std) of 16 rows (pass nt) -> B-frags out[4].
__device__ __forceinline__ void build_x2_pass(const float* sX, int strip, int nt, int l,
    const float* __restrict__ na, const float* __restrict__ nb, f16x8 out[4]) {
  const int l15 = l & 15, q = l >> 4;
  const int row = strip + nt * 16 + l15;
  float sum = 0.f, sq = 0.f;
#pragma unroll
  for (int c4 = 0; c4 < 8; ++c4) {
    f32x4 v = *(const f32x4*)&sX[XF(row, q * 32 + c4 * 4)];
#pragma unroll
    for (int e = 0; e < 4; ++e) { sum += v[e]; sq = fmaf(v[e], v[e], sq); }
  }
  sum += __shfl_xor(sum, 16); sum += __shfl_xor(sum, 32);
  sq  += __shfl_xor(sq, 16);  sq  += __shfl_xor(sq, 32);
  const float mu = sum * (1.f / 128.f);
  const float var = fmaf(-sum, mu, sq) * (1.f / 127.f);
  const float inv = 1.f / (sqrtf(var) + 1e-6f);
#pragma unroll
  for (int kt = 0; kt < 4; ++kt) {
    const int d0 = kt * 32 + q * 8;
    f32x4 xA = *(const f32x4*)&sX[XF(row, d0)];
    f32x4 xB = *(const f32x4*)&sX[XF(row, d0 + 4)];
    f32x4 nA = *(const f32x4*)&na[d0], nB = *(const f32x4*)&na[d0 + 4];
    f32x4 bA = *(const f32x4*)&nb[d0], bB = *(const f32x4*)&nb[d0 + 4];
    float v0 = fmaf(nA[0] * inv, xA[0] - mu, bA[0]);
    float v1 = fmaf(nA[1] * inv, xA[1] - mu, bA[1]);
    float v2 = fmaf(nA[2] * inv, xA[2] - mu, bA[2]);
    float v3 = fmaf(nA[3] * inv, xA[3] - mu, bA[3]);
    float v4 = fmaf(nB[0] * inv, xB[0] - mu, bB[0]);
    float v5 = fmaf(nB[1] * inv, xB[1] - mu, bB[1]);
    float v6 = fmaf(nB[2] * inv, xB[2] - mu, bB[2]);
    float v7 = fmaf(nB[3] * inv, xB[3] - mu, bB[3]);
    out[kt] = u4f16x8(pack2(v0, v1), pack2(v2, v3), pack2(v4, v5), pack2(v6, v7));
  }
}

// norm2 + FFN with LDS-staged weights. aux layout per c-chunk:
//   [0..8191]    w1c: 64 u-rows x 128 cols f16, granule swz g^(row&15)
//   [8192..16383] w2c: 128 d-rows x 64 u-cols f16, granule swz g^(row&7)
// Partial w2 outputs accumulate directly into sX (sX is the accumulator).
__device__ __forceinline__ void ffn_phase(float* sX, _Float16* aux, int t,
    int strip, int l, const float* __restrict__ na, const float* __restrict__ nb,
    const _Float16* __restrict__ w1, const float* __restrict__ b1,
    const _Float16* __restrict__ w2, const float* __restrict__ b2,
    int aLo, int aHi, int hiSel) {
  const int l15 = l & 15, lg = l >> 4;
  f16x8 x2f[4][2];
#pragma unroll
  for (int nt = 0; nt < 2; ++nt) {
    f16x8 tmp[4];
    build_x2_pass(sX, strip, nt, l, na, nb, tmp);
#pragma unroll
    for (int kt = 0; kt < 4; ++kt) x2f[kt][nt] = tmp[kt];
  }
  const int sr1 = t >> 4, sg1 = t & 15;       // w1 staging coords
  const int sr2 = t >> 3, sg2 = t & 7;        // w2 staging coords
#pragma unroll 1
  for (int c = 0; c < 8; ++c) {
    __syncthreads();
#pragma unroll
    for (int r = 0; r < 2; ++r) {
      const int row = r * 32 + sr1;
      f16x8 v = *(const f16x8*)(w1 + (c * 64 + row) * 128 + sg1 * 8);
      *(f16x8*)(aux + row * 128 + ((sg1 ^ (row & 15)) << 3)) = v;
    }
#pragma unroll
    for (int r = 0; r < 2; ++r) {
      const int row = r * 64 + sr2;
      f16x8 v = *(const f16x8*)(w2 + row * 512 + c * 64 + sg2 * 8);
      *(f16x8*)(aux + 8192 + row * 64 + ((sg2 ^ (row & 7)) << 3)) = v;
    }
    __syncthreads();
    // H = relu(w1c @ x2 + b1c)  (u-local 64 = 4 m-tiles)
    f32x4 hacc[4][2];
#pragma unroll
    for (int mt = 0; mt < 4; ++mt) {
      f32x4 b = *(const f32x4*)&b1[c * 64 + mt * 16 + lg * 4];
      hacc[mt][0] = b; hacc[mt][1] = b;
    }
#pragma unroll
    for (int mt = 0; mt < 4; ++mt)
#pragma unroll
      for (int kt = 0; kt < 4; ++kt) {
        f16x8 a = *(const f16x8*)(aux + (mt * 16 + l15) * 128 + (((kt * 4 + lg) ^ l15) << 3));
        hacc[mt][0] = MFMA(a, x2f[kt][0], hacc[mt][0]);
        hacc[mt][1] = MFMA(a, x2f[kt][1], hacc[mt][1]);
      }
#pragma unroll
    for (int mt = 0; mt < 4; ++mt)
#pragma unroll
      for (int nt = 0; nt < 2; ++nt)
#pragma unroll
        for (int e = 0; e < 4; ++e) hacc[mt][nt][e] = fmaxf(hacc[mt][nt][e], 0.f);
    f16x8 hf[2][2];
#pragma unroll
    for (int kt2 = 0; kt2 < 2; ++kt2) {
      hf[kt2][0] = make_bfrag(hacc[kt2 * 2][0], hacc[kt2 * 2 + 1][0], aLo, aHi, hiSel);
      hf[kt2][1] = make_bfrag(hacc[kt2 * 2][1], hacc[kt2 * 2 + 1][1], aLo, aHi, hiSel);
    }
    // w2c partial: all 128 d in two reg-halves; accumulate into sX
#pragma unroll 1
    for (int dh = 0; dh < 2; ++dh) {
      f32x4 oacc[4][2];
#pragma unroll
      for (int mt = 0; mt < 4; ++mt) {
        if (c == 0) {
          f32x4 b = *(const f32x4*)&b2[dh * 64 + mt * 16 + lg * 4];
          oacc[mt][0] = b; oacc[mt][1] = b;
        } else {
          f32x4 z = {0.f, 0.f, 0.f, 0.f};
          oacc[mt][0] = z; oacc[mt][1] = z;
        }
      }
#pragma unroll
      for (int kt2 = 0; kt2 < 2; ++kt2)
#pragma unroll
        for (int mt = 0; mt < 4; ++mt) {
          const int row = dh * 64 + mt * 16 + l15;
          f16x8 a = *(const f16x8*)(aux + 8192 + row * 64 + (((kt2 * 4 + lg) ^ (l15 & 7)) << 3));
          oacc[mt][0] = MFMA(a, hf[kt2][0], oacc[mt][0]);
          oacc[mt][1] = MFMA(a, hf[kt2][1], oacc[mt][1]);
        }
#pragma unroll
      for (int mt = 0; mt < 4; ++mt)
#pragma unroll
        for (int nt = 0; nt < 2; ++nt) {
          const int row = strip + nt * 16 + l15;
          float* dst = &sX[XF(row, dh * 64 + mt * 16 + lg * 4)];
          f32x4 v = *(const f32x4*)dst;
          v += oacc[mt][nt];
          *(f32x4*)dst = v;
        }
    }
  }
}

__global__ __launch_bounds__(512) void batchk(P2 p) {
  __shared__ __align__(16) float sX[32768];        // 128 KB, XF-swizzled
  __shared__ __align__(16) _Float16 sAux[16384];   // 32 KB: staged weights / K+VT

  const int t = threadIdx.x;
  const int i = blockIdx.x;
  const int l = t & 63;
  const int wv = t >> 6;
  const int strip = wv * 32;
  const int l15 = l & 15;
  const int lg = l >> 4;
  const int hiSel = (l >> 5) & 1;
  const int aLo = ((((lg & 1) * 2 + 0) * 16) + l15) * 4;
  const int aHi = ((((lg & 1) * 2 + 1) * 16) + l15) * 4;

  // ---- Phase A: X[i,j,:] = x0[j] + a0[i] (own strip rows) ----
  {
    const int j = t >> 1, hf = t & 1;
    const float* xr = p.x0 + j * 128 + hf * 64;
    const float* ar = p.a0 + i * 128 + hf * 64;
#pragma unroll
    for (int c = 0; c < 16; ++c) {
      f32x4 a = *(const f32x4*)(xr + c * 4);
      f32x4 b = *(const f32x4*)(ar + c * 4);
      a += b;
      *(f32x4*)&sX[XF(j, hf * 64 + c * 4)] = a;
    }
  }
  // no barrier needed: all sX traffic below is own-strip until attention LDS use

  // ---- FFN0 ----
  ffn_phase(sX, sAux, t, strip, l, p.n2a, p.n2b, p.w1h, p.b1, p.w2h, p.b2,
            aLo, aHi, hiSel);

  // ---- layer-1 attention ----
  {
    const _Float16* __restrict__ qw = p.wq + 16384;
    const _Float16* __restrict__ kw = p.wk + 16384;
    const _Float16* __restrict__ vw = p.wvv + 16384;
    const _Float16* __restrict__ ow = p.wo + 16384;
    const float* __restrict__ qb1 = p.qb + 128;
    const float* __restrict__ kb1 = p.kb + 128;
    const float* __restrict__ vb1 = p.vb + 128;
    const float* __restrict__ ob1 = p.ob + 128;

    f16x8 x2f[4][2];
#pragma unroll
    for (int nt = 0; nt < 2; ++nt) {
      f16x8 tmp[4];
      build_x2_pass(sX, strip, nt, l, p.n1a + 128, p.n1b + 128, tmp);
#pragma unroll
      for (int kt = 0; kt < 4; ++kt) x2f[kt][nt] = tmp[kt];
    }

    const int sr = t >> 4, sg = t & 15;   // weight staging coords (32x128)

#pragma unroll 1
    for (int h = 0; h < 4; ++h) {
      __syncthreads();
      // stage kw_h -> aux[0:4096], vw_h -> aux[4096:8192], qw_h -> aux[8192:12288]
      {
        f16x8 v0 = *(const f16x8*)(kw + (h * 32 + sr) * 128 + sg * 8);
        *(f16x8*)(sAux + sr * 128 + ((sg ^ (sr & 15)) << 3)) = v0;
        f16x8 v1 = *(const f16x8*)(vw + (h * 32 + sr) * 128 + sg * 8);
        *(f16x8*)(sAux + 4096 + sr * 128 + ((sg ^ (sr & 15)) << 3)) = v1;
        f16x8 v2 = *(const f16x8*)(qw + (h * 32 + sr) * 128 + sg * 8);
        *(f16x8*)(sAux + 8192 + sr * 128 + ((sg ^ (sr & 15)) << 3)) = v2;
      }
      __syncthreads();

      // ---- gen K, V, Q (A-frags from staged LDS) ----
      f32x4 kacc[2][2], vacc[2][2], qacc[2][2];
#pragma unroll
      for (int mt = 0; mt < 2; ++mt) {
        f32x4 kb4 = *(const f32x4*)&kb1[h * 32 + mt * 16 + lg * 4];
        f32x4 vb4 = *(const f32x4*)&vb1[h * 32 + mt * 16 + lg * 4];
        f32x4 qb4 = *(const f32x4*)&qb1[h * 32 + mt * 16 + lg * 4];
        kacc[mt][0] = kb4; kacc[mt][1] = kb4;
        vacc[mt][0] = vb4; vacc[mt][1] = vb4;
        qacc[mt][0] = qb4; qacc[mt][1] = qb4;
      }
#pragma unroll
      for (int mt = 0; mt < 2; ++mt)
#pragma unroll
        for (int kt = 0; kt < 4; ++kt) {
          const int off = (mt * 16 + l15) * 128 + (((kt * 4 + lg) ^ l15) << 3);
          f16x8 ak = *(const f16x8*)(sAux + off);
          f16x8 av = *(const f16x8*)(sAux + 4096 + off);
          f16x8 aq = *(const f16x8*)(sAux + 8192 + off);
          kacc[mt][0] = MFMA(ak, x2f[kt][0], kacc[mt][0]);
          kacc[mt][1] = MFMA(ak, x2f[kt][1], kacc[mt][1]);
          vacc[mt][0] = MFMA(av, x2f[kt][0], vacc[mt][0]);
          vacc[mt][1] = MFMA(av, x2f[kt][1], vacc[mt][1]);
          qacc[mt][0] = MFMA(aq, x2f[kt][0], qacc[mt][0]);
          qacc[mt][1] = MFMA(aq, x2f[kt][1], qacc[mt][1]);
        }
#pragma unroll
      for (int mt = 0; mt < 2; ++mt)
#pragma unroll
        for (int nt = 0; nt < 2; ++nt)
#pragma unroll
          for (int e = 0; e < 4; ++e) qacc[mt][nt][e] *= INV_SQRT_DK;
      f16x8 qf[2];
      qf[0] = make_bfrag(qacc[0][0], qacc[1][0], aLo, aHi, hiSel);
      qf[1] = make_bfrag(qacc[0][1], qacc[1][1], aLo, aHi, hiSel);
      __syncthreads();   // all waves done reading staged weights

      // ---- write K [256][32] @0, VT [32][256] @8192 (overwrite weights) ----
#pragma unroll
      for (int mt = 0; mt < 2; ++mt)
#pragma unroll
        for (int nt = 0; nt < 2; ++nt) {
          const int j = strip + nt * 16 + l15;
          const int db = mt * 16 + lg * 4;
          uint2 w;
          w.x = pack2(kacc[mt][nt][0], kacc[mt][nt][1]);
          w.y = pack2(kacc[mt][nt][2], kacc[mt][nt][3]);
          *(uint2*)(sAux + j * 32 + (db ^ ((j & 3) << 3))) = w;
#pragma unroll
          for (int e = 0; e < 4; ++e) {
            const int d = mt * 16 + lg * 4 + e;
            sAux[8192 + d * 256 + (j ^ ((d & 7) << 3))] = (_Float16)vacc[mt][nt][e];
          }
        }
      __syncthreads();   // K/VT visible

      // ---- flash over 8 k-tiles, both row-passes ----
#pragma unroll
      for (int nt = 0; nt < 2; ++nt) {
        float mrun = -3e38f, lsum = 0.f;
        f32x4 oacc[2];
        { f32x4 z = {0.f, 0.f, 0.f, 0.f}; oacc[0] = z; oacc[1] = z; }
#pragma unroll 1
        for (int ktile = 0; ktile < 8; ++ktile) {
          f32x4 sacc[2];
#pragma unroll
          for (int mt2 = 0; mt2 < 2; ++mt2) {
            const int k = ktile * 32 + mt2 * 16 + l15;
            f16x8 a = *(const f16x8*)(sAux + k * 32 + ((lg * 8) ^ ((k & 3) << 3)));
            f32x4 z = {0.f, 0.f, 0.f, 0.f};
            sacc[mt2] = MFMA(a, qf[nt], z);
          }
          float tm = -3e38f;
#pragma unroll
          for (int mt2 = 0; mt2 < 2; ++mt2)
#pragma unroll
            for (int e = 0; e < 4; ++e) tm = fmaxf(tm, sacc[mt2][e]);
          tm = fmaxf(tm, __shfl_xor(tm, 16));
          tm = fmaxf(tm, __shfl_xor(tm, 32));
          const float mnew = fmaxf(mrun, tm);
          const float corr = __expf(mrun - mnew);
          float ts = 0.f;
#pragma unroll
          for (int mt2 = 0; mt2 < 2; ++mt2)
#pragma unroll
            for (int e = 0; e < 4; ++e) {
              float ev = __expf(sacc[mt2][e] - mnew);
              sacc[mt2][e] = ev;
              ts += ev;
            }
          ts += __shfl_xor(ts, 16);
          ts += __shfl_xor(ts, 32);
          lsum = fmaf(lsum, corr, ts);
          oacc[0] *= corr; oacc[1] *= corr;
          f16x8 pf = make_bfrag(sacc[0], sacc[1], aLo, aHi, hiSel);
#pragma unroll
          for (int mt2 = 0; mt2 < 2; ++mt2) {
            const int d = mt2 * 16 + l15;
            f16x8 a = *(const f16x8*)(sAux + 8192 + d * 256 + ((ktile * 32 + lg * 8) ^ ((d & 7) << 3)));
            oacc[mt2] = MFMA(a, pf, oacc[mt2]);
          }
          mrun = mnew;
        }
        const float linv = 1.f / lsum;
        oacc[0] *= linv; oacc[1] *= linv;
        f16x8 of = make_bfrag(oacc[0], oacc[1], aLo, aHi, hiSel);
        // Z = ow_h @ O^T (ow from L2; 512KB/block total) + residual
        f32x4 zacc[8];
#pragma unroll
        for (int mt = 0; mt < 8; ++mt) {
          if (h == 0) zacc[mt] = *(const f32x4*)&ob1[mt * 16 + lg * 4];
          else { f32x4 z = {0.f, 0.f, 0.f, 0.f}; zacc[mt] = z; }
        }
#pragma unroll
        for (int mt = 0; mt < 8; ++mt) {
          f16x8 a = *(const f16x8*)(ow + (mt * 16 + l15) * 128 + h * 32 + lg * 8);
          zacc[mt] = MFMA(a, of, zacc[mt]);
        }
        const int row = strip + nt * 16 + l15;
#pragma unroll
        for (int mt = 0; mt < 8; ++mt) {
          float* dst = &sX[XF(row, mt * 16 + lg * 4)];
          f32x4 v = *(const f32x4*)dst;
          v += zacc[mt];
          *(f32x4*)dst = v;
        }
      }
      // next h's top barrier protects aux
    }
  }

  // ---- FFN1 ----
  ffn_phase(sX, sAux, t, strip, l, p.n2a + 128, p.n2b + 128,
            p.w1h + 65536, p.b1 + 512, p.w2h + 65536, p.b2 + 128,
            aLo, aHi, hiSel);

  // ---- final norm + output projection ----
  {
    const int r = strip + (l & 31), hf = l >> 5;
    float sum = 0.f, sq = 0.f;
#pragma unroll
    for (int c = 0; c < 16; ++c) {
      f32x4 v = *(const f32x4*)&sX[XF(r, hf * 64 + c * 4)];
#pragma unroll
      for (int e = 0; e < 4; ++e) { sum += v[e]; sq = fmaf(v[e], v[e], sq); }
    }
    sum += __shfl_xor(sum, 32);
    sq  += __shfl_xor(sq, 32);
    float mu = sum * (1.f / 128.f);
    float var = fmaf(-sum, mu, sq) * (1.f / 127.f);
    float inv = 1.f / (sqrtf(var) + 1e-6f);
    float os = 0.f;
#pragma unroll
    for (int c = 0; c < 16; ++c) {
      f32x4 x  = *(const f32x4*)&sX[XF(r, hf * 64 + c * 4)];
      f32x4 fa = *(const f32x4*)&p.fna[hf * 64 + c * 4];
      f32x4 fb = *(const f32x4*)&p.fnb[hf * 64 + c * 4];
      f32x4 wo = *(const f32x4*)&p.out_w[hf * 64 + c * 4];
#pragma unroll
      for (int e = 0; e < 4; ++e)
        os = fmaf(fmaf(fa[e] * inv, x[e] - mu, fb[e]), wo[e], os);
    }
    os += __shfl_xor(os, 32);
    if (l < 32) p.out[i * 256 + r] = os + p.out_b[0];
  }
}

// ---------------- host ----------------
extern "C" void kernel_launch(void* const* d_in, const int* in_sizes, int n_in,
                              void* d_out, int out_size, void* d_ws, size_t ws_size,
                              hipStream_t stream) {
  float* x0 = (float*)d_ws;                           // 32768 f32
  float* a0 = x0 + 32768;                             // 32768 f32
  _Float16* W16 = (_Float16*)((char*)d_ws + 262144);  // 393216 halves

  P0 p0;
  p0.qw = (const float*)d_in[8];  p0.kw = (const float*)d_in[10];
  p0.vw = (const float*)d_in[12]; p0.ow = (const float*)d_in[14];
  p0.w1 = (const float*)d_in[20]; p0.w2 = (const float*)d_in[22];
  p0.dst = W16;
  convf16<<<dim3(1536), dim3(256), 0, stream>>>(p0);

  P1 p1;
  p1.src  = (const float*)d_in[0];
  p1.t    = (const int*)  d_in[1];
  p1.fc_w = (const float*)d_in[2];  p1.fc_b = (const float*)d_in[3];
  p1.gc_w = (const float*)d_in[4];  p1.gc_b = (const float*)d_in[5];
  p1.ln_w = (const float*)d_in[6];  p1.ln_b = (const float*)d_in[7];
  p1.n1a  = (const float*)d_in[16]; p1.n1b  = (const float*)d_in[17];
  p1.vw   = (const float*)d_in[12]; p1.vb   = (const float*)d_in[13];
  p1.ow   = (const float*)d_in[14]; p1.ob   = (const float*)d_in[15];
  p1.x0 = x0; p1.a0 = a0;
  prep<<<dim3(128), dim3(256), 0, stream>>>(p1);

  P2 p2;
  p2.x0 = x0; p2.a0 = a0;
  p2.wq  = W16;
  p2.wk  = W16 + 32768;
  p2.wvv = W16 + 65536;
  p2.wo  = W16 + 98304;
  p2.w1h = W16 + 131072;
  p2.w2h = W16 + 262144;
  p2.qb = (const float*)d_in[9];  p2.kb = (const float*)d_in[11];
  p2.vb = (const float*)d_in[13]; p2.ob = (const float*)d_in[15];
  p2.n1a = (const float*)d_in[16]; p2.n1b = (const float*)d_in[17];
  p2.n2a = (const float*)d_in[18]; p2.n2b = (const float*)d_in[19];
  p2.b1 = (const float*)d_in[21];  p2.b2 = (const float*)d_in[23];
  p2.fna = (const float*)d_in[24]; p2.fnb = (const float*)d_in[25];
  p2.out_w = (const float*)d_in[26]; p2.out_b = (const float*)d_in[27];
  p2.out = (float*)d_out;
  batchk<<<dim3(256), dim3(512), 0, stream>>>(p2);
}